// Round 1
// baseline (247.725 us; speedup 1.0000x reference)
//
#include <hip/hip_runtime.h>

typedef __bf16 bf16x8 __attribute__((ext_vector_type(8)));
typedef __bf16 bf16x4 __attribute__((ext_vector_type(4)));
typedef float f32x4 __attribute__((ext_vector_type(4)));

typedef const __attribute__((address_space(1))) void* gptr_t;
typedef __attribute__((address_space(3))) void* lptr_t;

__device__ __forceinline__ f32x4 mfma16(bf16x8 a, bf16x8 b, f32x4 c) {
  return __builtin_amdgcn_mfma_f32_16x16x32_bf16(a, b, c, 0, 0, 0);
}

__device__ __forceinline__ void load_lds16(const __bf16* g, __bf16* l) {
  __builtin_amdgcn_global_load_lds((gptr_t)g, (lptr_t)l, 16, 0, 0);
}

__device__ __forceinline__ float fast_exp2(float x) {
#if __has_builtin(__builtin_amdgcn_exp2f)
  return __builtin_amdgcn_exp2f(x);  // raw v_exp_f32
#else
  return exp2f(x);
#endif
}

// round-to-nearest(+away) f32->bf16 for two values, packed into one dword
__device__ __forceinline__ unsigned pack_bf16(float f0, float f1) {
  unsigned u0 = __builtin_bit_cast(unsigned, f0) + 0x8000u;
  unsigned u1 = __builtin_bit_cast(unsigned, f1) + 0x8000u;
  return __builtin_amdgcn_perm(u1, u0, 0x07060302);
}

// ---- fp32 -> bf16 pre-convert: x (4096 blks), qkv_w (1536), out_w (512) ----
__global__ __launch_bounds__(256) void convert3(
    const float* __restrict__ x, const float* __restrict__ w1,
    const float* __restrict__ w2, __bf16* __restrict__ xb,
    __bf16* __restrict__ w1b, __bf16* __restrict__ w2b) {
  int bid = blockIdx.x;
  const float* src;
  __bf16* dst;
  int base;
  if (bid < 4096) {
    src = x; dst = xb; base = bid;
  } else if (bid < 5632) {
    src = w1; dst = w1b; base = bid - 4096;
  } else {
    src = w2; dst = w2b; base = bid - 5632;
  }
  size_t off = (size_t)base * 2048 + threadIdx.x * 8;
  float4 v0 = *(const float4*)(src + off);
  float4 v1 = *(const float4*)(src + off + 4);
  bf16x8 o = {(__bf16)v0.x, (__bf16)v0.y, (__bf16)v0.z, (__bf16)v0.w,
              (__bf16)v1.x, (__bf16)v1.y, (__bf16)v1.z, (__bf16)v1.w};
  *(bf16x8*)(dst + off) = o;
}

// C[M][N] = A[M][K] @ B[N][K]^T + bias[N]; A,B bf16; C bf16 or fp32.
// Deep-pipelined counted-vmcnt schedule (T3+T4+T5):
//   BM=256 x BN=128 tile, 8 waves (512 thr), per-wave 64x64 (identical
//   fragment/epilogue code to the proven 128^2 kernel). BK=32, ring-4 LDS
//   buffers (96 KiB), prefetch distance 2 K-tiles.
// Per K-tile phase: {8 ds_read_b128 || 3 global_load_lds(16B, tile j+2) ->
//   s_barrier -> lgkmcnt(0) -> setprio(1) -> 16 MFMA -> setprio(0) ->
//   vmcnt(3) -> s_barrier}.  vmcnt never drains to 0 in the main loop;
// loads are in flight ~2 phases (>= HBM latency) before their wait.
// Ring-4 distance-2 => staged writes always target a buffer whose last
// reader finished >=2 barriers ago (no overwrite hazard).
// Chunk swizzle (proven): LDS[row][c] = G[row][c ^ ((row>>1)&3)]; fragment
// read at chunk quad ^ ((l15>>1)&3) => <=2-way bank aliasing (free).
template <bool C_BF16>
__global__ __launch_bounds__(512) void gemm256(
    const __bf16* __restrict__ A, const __bf16* __restrict__ B,
    const float* __restrict__ bias, void* __restrict__ Cv, int N, int K,
    int qcols) {
  __shared__ __bf16 As[4][256 * 32];  // 64 KiB
  __shared__ __bf16 Bs[4][128 * 32];  // 32 KiB

  const int tid = threadIdx.x;
  const int wid = tid >> 6;   // 0..7
  const int lane = tid & 63;
  const int l15 = lane & 15;
  const int quad = lane >> 4;
  const int wr = wid >> 1;    // 0..3 (M)
  const int wc = wid & 1;     // 0..1 (N)

  // XCD-aware bijective swizzle (both call sites have nwg % 8 == 0):
  // consecutive new-ids land on one XCD -> A-panel stays hot in its L2.
  const int nwg = gridDim.x * gridDim.y;
  int id = blockIdx.y * gridDim.x + blockIdx.x;
  id = (id & 7) * (nwg >> 3) + (id >> 3);
  const int bn = (id % gridDim.x) * 128;
  const int bm = (id / gridDim.x) * 256;

  // staging: thread t -> row tid>>2, global chunk (tid&3)^((tid>>3)&3)
  const int srow = tid >> 2;  // 0..127
  const int schunk = ((tid & 3) ^ ((tid >> 3) & 3)) * 8;
  const __bf16* gA = A + (size_t)(bm + srow) * K + schunk;
  const __bf16* gB = B + (size_t)(bn + srow) * K + schunk;
  const int a_st0 = wid * 512;         // rows [0,128)
  const int a_st1 = 4096 + wid * 512;  // rows [128,256)
  const int b_st = wid * 512;          // rows [0,128)

  // fragment-read offsets (loop-invariant; (row>>1)&3 == (l15>>1)&3 here)
  const int fsl = (quad ^ ((l15 >> 1) & 3)) * 8;
  int af_off[4], bf_off[4];
#pragma unroll
  for (int mt = 0; mt < 4; ++mt)
    af_off[mt] = (wr * 64 + mt * 16 + l15) * 32 + fsl;
#pragma unroll
  for (int nt = 0; nt < 4; ++nt)
    bf_off[nt] = (wc * 64 + nt * 16 + l15) * 32 + fsl;

  f32x4 acc[4][4] = {};

  // prologue: stage tiles 0 and 1 (3 loads each); wait tile 0 only.
  load_lds16(gA, &As[0][a_st0]);
  load_lds16(gA + (size_t)128 * K, &As[0][a_st1]);
  load_lds16(gB, &Bs[0][b_st]);
  load_lds16(gA + 32, &As[1][a_st0]);
  load_lds16(gA + 32 + (size_t)128 * K, &As[1][a_st1]);
  load_lds16(gB + 32, &Bs[1][b_st]);
  asm volatile("s_waitcnt vmcnt(3)" ::: "memory");
  __builtin_amdgcn_s_barrier();

  const int ntt = K >> 5;
  for (int j = 0; j < ntt; ++j) {
    const __bf16* ab = As[j & 3];
    const __bf16* bb = Bs[j & 3];
    bf16x8 af[4], bf[4];
#pragma unroll
    for (int mt = 0; mt < 4; ++mt)
      af[mt] = *(const bf16x8*)(ab + af_off[mt]);
#pragma unroll
    for (int nt = 0; nt < 4; ++nt)
      bf[nt] = *(const bf16x8*)(bb + bf_off[nt]);
    const bool more = (j + 2 < ntt);
    if (more) {
      const int sb = (j + 2) & 3;
      const size_t koff = (size_t)(j + 2) << 5;
      load_lds16(gA + koff, &As[sb][a_st0]);
      load_lds16(gA + koff + (size_t)128 * K, &As[sb][a_st1]);
      load_lds16(gB + koff, &Bs[sb][b_st]);
    }
    __builtin_amdgcn_s_barrier();
    asm volatile("s_waitcnt lgkmcnt(0)" ::: "memory");
    __builtin_amdgcn_sched_barrier(0);
    __builtin_amdgcn_s_setprio(1);
#pragma unroll
    for (int mt = 0; mt < 4; ++mt)
#pragma unroll
      for (int nt = 0; nt < 4; ++nt)
        acc[mt][nt] = mfma16(af[mt], bf[nt], acc[mt][nt]);
    __builtin_amdgcn_s_setprio(0);
    if (more)
      asm volatile("s_waitcnt vmcnt(3)" ::: "memory");  // tile j+1 landed
    else
      asm volatile("s_waitcnt vmcnt(0)" ::: "memory");  // epilogue drain
    __builtin_amdgcn_s_barrier();
  }

  const float sc = (bn < qcols) ? 0.18033688011112043f : 1.0f;
#pragma unroll
  for (int mt = 0; mt < 4; ++mt) {
#pragma unroll
    for (int nt = 0; nt < 4; ++nt) {
      int gc = bn + wc * 64 + nt * 16 + l15;
      float bv = bias[gc];
#pragma unroll
      for (int r = 0; r < 4; ++r) {
        int gr = bm + wr * 64 + mt * 16 + quad * 4 + r;
        float val = (acc[mt][nt][r] + bv) * sc;
        if constexpr (C_BF16)
          ((__bf16*)Cv)[(size_t)gr * N + gc] = (__bf16)val;
        else
          ((float*)Cv)[(size_t)gr * N + gc] = val;
      }
    }
  }
}

// exp + (optional causal mask) + deferred-l + packed P store in pi-layout.
template <bool MASK>
__device__ __forceinline__ void softmax_block(f32x4 (&s)[2][4],
                                              float (&lsum)[2][4],
                                              __bf16* __restrict__ psw,
                                              int kv0, int qrow_base, int quad,
                                              int l15) {
#pragma unroll
  for (int mt = 0; mt < 2; ++mt) {
#pragma unroll
    for (int r = 0; r < 4; ++r) {
      int prow = mt * 16 + quad * 4 + r;
      float p[4];
#pragma unroll
      for (int nt = 0; nt < 4; ++nt) {
        p[nt] = fast_exp2(s[mt][nt][r]);  // scale pre-folded into Q
        if constexpr (MASK) {
          if ((kv0 + nt * 16 + l15) > (qrow_base + prow)) p[nt] = 0.f;
        }
      }
      lsum[mt][r] += (p[0] + p[1]) + (p[2] + p[3]);
      uint2 w = {pack_bf16(p[0], p[1]), pack_bf16(p[2], p[3])};
      int o = ((l15 >> 1) ^ (prow & 7)) & 7;
      *(uint2*)(psw + prow * 64 + o * 8 + 4 * (l15 & 1)) = w;
    }
  }
}

// Flash attention, causal. qkv: (B*T, 3072) bf16 (Q pre-scaled by log2e/8);
// out: (B*T, 1024) bf16. Grid (64 bh, 8 pb) bh-fastest (KV L2-resident per
// XCD). Block 256 = 4 waves, BQ=128, BKV=64; phases {pb, 15-pb} -> 34 iters.
// P/V k-index permuted by pi(k)=4*(k&15)+(k>>4) -> packed P stores; XOR
// octet swizzles keep LDS bank-uniform. No-max softmax, deferred l.
// All LDS fragment offsets precomputed outside the kv-loop.
__global__ __launch_bounds__(256) void attn_kernel(
    const __bf16* __restrict__ qkv, __bf16* __restrict__ out) {
  constexpr int T = 2048, C3 = 3072;
  constexpr int KVSTEP = 64 * C3;
  __shared__ __bf16 Ks[2][64 * 64];  // [kv][d]
  __shared__ __bf16 Vt[2][64 * 64];  // [d][pi(kv)]
  __shared__ __bf16 Ps[4][32 * 64];  // per-wave [qrow][pi(kv)]

  const int tid = threadIdx.x;
  const int wid = tid >> 6;
  const int lane = tid & 63;
  const int l15 = lane & 15;
  const int quad = lane >> 4;
  const int bh = blockIdx.x;  // 0..63 (fastest -> same XCD per bh)
  const int pb = blockIdx.y;  // 0..7
  const int b = bh >> 4, h = bh & 15;
  const size_t rowbase = (size_t)b * T;

  const int kr = tid >> 3;  // K staging: rows kr, kr+32
  const int kc = tid & 7;   // d-octet
  const int vj = tid >> 4;  // V staging: rows vj+16i -> pi-cols 4vj+i
  const int vn = tid & 15;  // d-nibble

  const __bf16* gk_base = qkv + rowbase * C3 + 1024 + h * 64 + kr * C3 + kc * 8;
  const __bf16* gv_base = qkv + rowbase * C3 + 2048 + h * 64 + vj * C3 + vn * 4;

  // ---- loop-invariant LDS offsets (elements) ----
  int ks_st0 = kr * 64 + ((kc ^ (kr & 7)) * 8);            // K store row kr
  int ks_st1 = (kr + 32) * 64 + ((kc ^ ((kr + 32) & 7)) * 8);
  int vt_st[4];
#pragma unroll
  for (int dd = 0; dd < 4; ++dd) {
    int d = 4 * vn + dd;
    vt_st[dd] = d * 64 + ((((vj >> 1) ^ (d & 7) ^ (d >> 3)) & 7) * 8) +
                4 * (vj & 1);
  }
  int kf_off[4][2];
#pragma unroll
  for (int nt = 0; nt < 4; ++nt)
#pragma unroll
    for (int ksi = 0; ksi < 2; ++ksi)
      kf_off[nt][ksi] =
          (nt * 16 + l15) * 64 + (((4 * ksi + quad) ^ (l15 & 7)) * 8);
  int pf_off[2][2];
#pragma unroll
  for (int mt = 0; mt < 2; ++mt)
#pragma unroll
    for (int ksi = 0; ksi < 2; ++ksi)
      pf_off[mt][ksi] =
          (mt * 16 + l15) * 64 + (((4 * ksi + quad) ^ (l15 & 7)) * 8);
  int vf_off[4][2];
#pragma unroll
  for (int ntv = 0; ntv < 4; ++ntv)
#pragma unroll
    for (int ksi = 0; ksi < 2; ++ksi) {
      int d = ntv * 16 + l15;
      vf_off[ntv][ksi] =
          d * 64 + ((((4 * ksi + quad) ^ (d & 7) ^ (d >> 3)) & 7) * 8);
    }

#pragma unroll 1
  for (int phase = 0; phase < 2; ++phase) {
    const int qp = phase == 0 ? pb : 15 - pb;
    const int q0 = qp * 128;
    const int ntiles = 2 * qp + 2;
    const int qrow_base = q0 + wid * 32;

    bf16x8 qf[2][2];
#pragma unroll
    for (int mt = 0; mt < 2; ++mt)
#pragma unroll
      for (int ksi = 0; ksi < 2; ++ksi)
        qf[mt][ksi] = *(const bf16x8*)(
            qkv + (rowbase + qrow_base + mt * 16 + l15) * C3 + h * 64 +
            ksi * 32 + quad * 8);

    f32x4 acc[2][4] = {};
    float lsum[2][4] = {};

    const __bf16* gk = gk_base;
    const __bf16* gv = gv_base;

    bf16x8 kreg[2];
    bf16x4 vreg[4];
    kreg[0] = *(const bf16x8*)(gk);
    kreg[1] = *(const bf16x8*)(gk + 32 * C3);
#pragma unroll
    for (int i = 0; i < 4; ++i)
      vreg[i] = *(const bf16x4*)(gv + i * 16 * C3);

    __syncthreads();  // previous phase's readers done

    for (int j = 0; j < ntiles; ++j) {
      __bf16* ksb = Ks[j & 1];
      __bf16* vtb = Vt[j & 1];
      *(bf16x8*)(ksb + ks_st0) = kreg[0];
      *(bf16x8*)(ksb + ks_st1) = kreg[1];
#pragma unroll
      for (int dd = 0; dd < 4; ++dd) {
        bf16x4 t = {vreg[0][dd], vreg[1][dd], vreg[2][dd], vreg[3][dd]};
        *(bf16x4*)(vtb + vt_st[dd]) = t;
      }
      if (j + 1 < ntiles) {
        gk += KVSTEP;
        gv += KVSTEP;
        kreg[0] = *(const bf16x8*)(gk);
        kreg[1] = *(const bf16x8*)(gk + 32 * C3);
#pragma unroll
        for (int i = 0; i < 4; ++i)
          vreg[i] = *(const bf16x4*)(gv + i * 16 * C3);
      }
      __syncthreads();

      const int kv0 = j * 64;
      // ---- S = Q K^T ----
      f32x4 s[2][4] = {};
#pragma unroll
      for (int nt = 0; nt < 4; ++nt) {
#pragma unroll
        for (int ksi = 0; ksi < 2; ++ksi) {
          bf16x8 kf = *(const bf16x8*)(ksb + kf_off[nt][ksi]);
#pragma unroll
          for (int mt = 0; mt < 2; ++mt)
            s[mt][nt] = mfma16(qf[mt][ksi], kf, s[mt][nt]);
        }
      }
      // ---- softmax (wave-uniform mask branch) ----
      if ((kv0 + 63) > qrow_base)
        softmax_block<true>(s, lsum, Ps[wid], kv0, qrow_base, quad, l15);
      else
        softmax_block<false>(s, lsum, Ps[wid], kv0, qrow_base, quad, l15);

      // ---- O += P V (per-wave Ps: no barrier) ----
#pragma unroll
      for (int ksi = 0; ksi < 2; ++ksi) {
        bf16x8 pf[2];
#pragma unroll
        for (int mt = 0; mt < 2; ++mt)
          pf[mt] = *(const bf16x8*)(Ps[wid] + pf_off[mt][ksi]);
#pragma unroll
        for (int ntv = 0; ntv < 4; ++ntv) {
          bf16x8 vf = *(const bf16x8*)(vtb + vf_off[ntv][ksi]);
#pragma unroll
          for (int mt = 0; mt < 2; ++mt)
            acc[mt][ntv] = mfma16(pf[mt], vf, acc[mt][ntv]);
        }
      }
    }

    // ---- phase epilogue: reduce l, normalize, store ----
#pragma unroll
    for (int mt = 0; mt < 2; ++mt)
#pragma unroll
      for (int r = 0; r < 4; ++r) {
        float l = lsum[mt][r];
        l += __shfl_xor(l, 1);
        l += __shfl_xor(l, 2);
        l += __shfl_xor(l, 4);
        l += __shfl_xor(l, 8);
        float inv = 1.0f / l;
        int row = qrow_base + mt * 16 + quad * 4 + r;
        size_t ob = (rowbase + row) * 1024 + h * 64;
#pragma unroll
        for (int ntv = 0; ntv < 4; ++ntv)
          out[ob + ntv * 16 + l15] = (__bf16)(acc[mt][ntv][r] * inv);
      }
  }
}

extern "C" void kernel_launch(void* const* d_in, const int* in_sizes, int n_in,
                              void* d_out, int out_size, void* d_ws,
                              size_t ws_size, hipStream_t stream) {
  const float* x = (const float*)d_in[0];
  const float* qkv_w = (const float*)d_in[1];
  const float* qkv_b = (const float*)d_in[2];
  const float* out_w = (const float*)d_in[3];
  const float* out_b = (const float*)d_in[4];
  float* out = (float*)d_out;

  __bf16* qkv_ws = (__bf16*)d_ws;                  // 8192*3072
  __bf16* attn_ws = qkv_ws + (size_t)8192 * 3072;  // 8192*1024
  __bf16* xb = attn_ws + (size_t)8192 * 1024;      // 8192*1024
  __bf16* wqb = xb + (size_t)8192 * 1024;          // 3072*1024
  __bf16* wob = wqb + (size_t)3072 * 1024;         // 1024*1024

  convert3<<<6144, 256, 0, stream>>>(x, qkv_w, out_w, xb, wqb, wob);
  // QKV: M=8192, N=3072 -> grid 24x32 = 768 blocks = 3 full rounds @1/CU
  gemm256<true><<<dim3(24, 32), 512, 0, stream>>>(xb, wqb, qkv_b, qkv_ws,
                                                  3072, 1024, 1024);
  attn_kernel<<<dim3(64, 8), 256, 0, stream>>>(qkv_ws, attn_ws);
  // out-proj: M=8192, N=1024 -> grid 8x32 = 256 blocks = 1 full round @1/CU
  gemm256<false><<<dim3(8, 32), 512, 0, stream>>>(attn_ws, wob, out_b, out,
                                                  1024, 1024, 0);
}